// Round 7
// baseline (317.650 us; speedup 1.0000x reference)
//
#include <hip/hip_runtime.h>
#include <cstdint>
#include <cstddef>

// Problem constants (reference: B=4, N=2048, DIM=256, heads=8, groups=2)
#define B_    4
#define NPT   2048
#define DIM_  256
#define QKVW  768   // 3*DIM

typedef unsigned short ushort_t;
typedef short bf16x8 __attribute__((ext_vector_type(8)));
typedef float f32x4 __attribute__((ext_vector_type(4)));

__device__ __forceinline__ float gelu_f(float x) {
  return 0.5f * x * (1.0f + erff(x * 0.70710678118654752440f));
}

// Fast gelu: A&S 7.1.26 erf (max abs err 1.5e-7). Used in GEMM epilogue.
__device__ __forceinline__ float gelu_fast(float x) {
  const float is2 = 0.70710678118654752440f;
  float z = x * is2;
  float az = __builtin_fabsf(z);
  float t = __builtin_amdgcn_rcpf(fmaf(0.3275911f, az, 1.0f));
  float p = fmaf(1.061405429f, t, -1.453152027f);
  p = fmaf(p, t, 1.421413741f);
  p = fmaf(p, t, -0.284496736f);
  p = fmaf(p, t, 0.254829592f);
  p = p * t;
  float e = __expf(-az * az);
  float er = fmaf(-p, e, 1.0f);
  er = __builtin_copysignf(er, x);
  return 0.5f * x * (1.0f + er);
}

// tanh-form gelu (~11 VALU; max abs dev from erf-gelu ~1e-3, fine at 3.7e-2
// threshold). Used only in attn's 50M rp evaluations.
__device__ __forceinline__ float gelu_tanh(float x) {
  float x2 = x * x;
  float z2 = x * fmaf(0.0713548163f, x2, 1.5957691216f);  // 2*sqrt(2/pi)*(x+0.044715x^3)
  float e = __expf(z2);
  float t = __builtin_amdgcn_rcpf(e + 1.0f);
  float th = fmaf(-2.0f, t, 1.0f);                        // tanh
  return 0.5f * x * (1.0f + th);
}

// fp32 -> bf16 round-to-nearest-even
__device__ __forceinline__ ushort_t f2bf(float f) {
  unsigned u = __float_as_uint(f);
  unsigned r = (u + 0x7fffu + ((u >> 16) & 1u)) >> 16;
  return (ushort_t)r;
}
__device__ __forceinline__ float bf2f(ushort_t h) {
  return __uint_as_float(((unsigned)h) << 16);
}

// One DPP min-reduce step on a 64-bit key split into (hi,lo) halves (KNN).
template <int CTRL>
__device__ __forceinline__ void dppmin_step(int& lo, int& hi) {
  int olo = __builtin_amdgcn_update_dpp(lo, lo, CTRL, 0xf, 0xf, false);
  int ohi = __builtin_amdgcn_update_dpp(hi, hi, CTRL, 0xf, 0xf, false);
  unsigned long long o = ((unsigned long long)(unsigned)ohi << 32) | (unsigned)olo;
  unsigned long long c = ((unsigned long long)(unsigned)hi << 32) | (unsigned)lo;
  if (o < c) { lo = olo; hi = ohi; }
}

template <int CTRL>
__device__ __forceinline__ float dpp_addf(float x) {
  int s = __builtin_amdgcn_update_dpp(0, __float_as_int(x), CTRL, 0xf, 0xf, false);
  return x + __int_as_float(s);
}

// ---------------------------------------------------------------------------
// Convert: xbf = bf16(x); W*T = bf16(W^T) (k-contig = MFMA B format);
// zero the colsum accumulator (ws is poisoned 0xAA before every launch).
// ---------------------------------------------------------------------------
#define XLEN  2097152   // 8192*256
#define QLEN  196608    // 768*256
#define PLEN  65536     // 256*256
__global__ __launch_bounds__(256) void convert_kernel(
    const float* __restrict__ x, const float* __restrict__ Wqkv,
    const float* __restrict__ Wproj, const float* __restrict__ Whead,
    ushort_t* __restrict__ xbf, ushort_t* __restrict__ WqkvT,
    ushort_t* __restrict__ WprojT, ushort_t* __restrict__ WheadT,
    float* __restrict__ part) {
  int i = blockIdx.x * 256 + threadIdx.x;
  if (i < 1024) part[i] = 0.f;  // gemm1 epilogue atomicAdd target
  if (i < XLEN) {
    xbf[i] = f2bf(x[i]);
  } else if (i < XLEN + QLEN) {
    int e = i - XLEN; int n = e >> 8, k = e & 255;
    WqkvT[e] = f2bf(Wqkv[k * 768 + n]);
  } else if (i < XLEN + QLEN + PLEN) {
    int e = i - XLEN - QLEN; int n = e >> 8, k = e & 255;
    WprojT[e] = f2bf(Wproj[k * 256 + n]);
  } else {
    int e = i - XLEN - QLEN - PLEN; int n = e >> 8, k = e & 255;
    WheadT[e] = f2bf(Whead[k * 256 + n]);
  }
}

// ---------------------------------------------------------------------------
// KNN: ONE WAVE per query. Packed key=(dist_bits<<32)|idx, DPP wave-min.
// ---------------------------------------------------------------------------
__global__ __launch_bounds__(256) void knn_kernel(const float* __restrict__ pos,
                                                  int* __restrict__ idx_out) {
  int wq = blockIdx.x * 4 + (threadIdx.x >> 6);
  int lane = threadIdx.x & 63;
  int b = wq >> 11, n = wq & (NPT - 1);
  const float* pb = pos + (size_t)b * NPT * 3;
  float qx = pb[n * 3 + 0], qy = pb[n * 3 + 1], qz = pb[n * 3 + 2];

  unsigned long long keys[32];
  {
#pragma clang fp contract(off)
#pragma unroll
    for (int s = 0; s < 32; s++) {
      int j = lane + (s << 6);
      float dx = qx - pb[j * 3 + 0];
      float dy = qy - pb[j * 3 + 1];
      float dz = qz - pb[j * 3 + 2];
      float d = dx * dx;
      d = d + dy * dy;
      d = d + dz * dz;
      keys[s] = ((unsigned long long)__float_as_uint(d) << 32) | (unsigned int)j;
    }
  }
  unsigned long long gk[4];
#pragma unroll
  for (int gi = 0; gi < 4; gi++) {
    unsigned long long m = keys[gi * 8];
#pragma unroll
    for (int s = 1; s < 8; s++) {
      unsigned long long c = keys[gi * 8 + s];
      m = (c < m) ? c : m;
    }
    gk[gi] = m;
  }
  unsigned long long lkey = gk[0];
#pragma unroll
  for (int gi = 1; gi < 4; gi++) lkey = (gk[gi] < lkey) ? gk[gi] : lkey;

  int* outp = idx_out + (size_t)wq * 32;
  for (int r = 0; r < 32; r++) {
    int lo = (int)(unsigned)(lkey & 0xffffffffULL);
    int hi = (int)(unsigned)(lkey >> 32);
    dppmin_step<0x111>(lo, hi);
    dppmin_step<0x112>(lo, hi);
    dppmin_step<0x114>(lo, hi);
    dppmin_step<0x118>(lo, hi);
    dppmin_step<0x142>(lo, hi);
    dppmin_step<0x143>(lo, hi);
    unsigned int glo = (unsigned int)__builtin_amdgcn_readlane(lo, 63);
    unsigned int ghi = (unsigned int)__builtin_amdgcn_readlane(hi, 63);
    unsigned long long g = ((unsigned long long)ghi << 32) | glo;
    if (lkey == g) {
      outp[r] = (int)glo;
#pragma unroll
      for (int gi = 0; gi < 4; gi++) {
        if (gk[gi] == g) {
          unsigned long long m = ~0ULL;
#pragma unroll
          for (int s = 0; s < 8; s++) {
            unsigned long long c = keys[gi * 8 + s];
            if (c == g) { c = ~0ULL; keys[gi * 8 + s] = c; }
            m = (c < m) ? c : m;
          }
          gk[gi] = m;
        }
      }
      lkey = gk[0];
#pragma unroll
      for (int gi = 1; gi < 4; gi++) lkey = (gk[gi] < lkey) ? gk[gi] : lkey;
    }
  }
}

// ---------------------------------------------------------------------------
// Register-file MFMA GEMM: ONE 64-thread wave per 64x64 tile, K=256. No LDS,
// no barriers — A/B fragments are loaded straight from global (dwordx4) and
// software-pipelined; at 512..1536 one-wave blocks the latency hides in TLP.
// (R6's m97-style LDS kernel was latency-serial: vmcnt(0)+2 barriers per
// k-iter at 0.5-1.5 blocks/CU, while the MFMA work itself is ~0.1-0.3 µs.)
// A bf16 [M][256]; BT bf16 [N][256] (k-contig). MFMA 16x16x32:
//   A-frag: lane = m(0..15) | quad -> k-octet;  B-frag identical on BT rows.
// MODE 0: C = acc                    (qkv, N=768)
// MODE 1: C = gelu(acc+bias), += colsum via atomics (feats_proj)
// MODE 2: C = extra + acc + bias     (head; BT = per-batch av-scaled WheadT)
// ---------------------------------------------------------------------------
template <int MODE>
__global__ __launch_bounds__(64) void gemm_rf(
    const ushort_t* __restrict__ A, const ushort_t* __restrict__ BT,
    const float* __restrict__ bias, const float* __restrict__ extra,
    float* __restrict__ C, float* __restrict__ part, int N) {
  constexpr int K = 256;
  int lane = threadIdx.x;
  int quad = lane >> 4, r16 = lane & 15;
  int m0 = blockIdx.y * 64, n0 = blockIdx.x * 64;
  int batch = m0 >> 11;
  const ushort_t* Ap = A + (size_t)(m0 + r16) * K + quad * 8;
  const ushort_t* Bp = (MODE == 2)
      ? BT + ((size_t)batch * N + n0 + r16) * K + quad * 8
      : BT + (size_t)(n0 + r16) * K + quad * 8;

  f32x4 acc[4][4] = {};
  bf16x8 af[4], bf[4], af2[4], bf2[4];
#pragma unroll
  for (int i = 0; i < 4; i++) {
    af[i] = *(const bf16x8*)(Ap + (size_t)i * 16 * K);
    bf[i] = *(const bf16x8*)(Bp + (size_t)i * 16 * K);
  }
#pragma unroll
  for (int kc = 0; kc < 8; kc++) {
    if (kc < 7) {
      int ko = (kc + 1) * 32;
#pragma unroll
      for (int i = 0; i < 4; i++) {
        af2[i] = *(const bf16x8*)(Ap + (size_t)i * 16 * K + ko);
        bf2[i] = *(const bf16x8*)(Bp + (size_t)i * 16 * K + ko);
      }
    }
#pragma unroll
    for (int i = 0; i < 4; i++)
#pragma unroll
      for (int j = 0; j < 4; j++)
        acc[i][j] = __builtin_amdgcn_mfma_f32_16x16x32_bf16(
            af[i], bf[j], acc[i][j], 0, 0, 0);
#pragma unroll
    for (int i = 0; i < 4; i++) { af[i] = af2[i]; bf[i] = bf2[i]; }
  }
  // epilogue: C/D layout col=lane&15, row=quad*4+reg
  float cs[4] = {};
#pragma unroll
  for (int i = 0; i < 4; i++) {
#pragma unroll
    for (int j = 0; j < 4; j++) {
      int col = n0 + j * 16 + r16;
#pragma unroll
      for (int r = 0; r < 4; r++) {
        int row = m0 + i * 16 + quad * 4 + r;
        float v = acc[i][j][r];
        if (MODE == 1) { v = gelu_fast(v + bias[col]); cs[j] += v; }
        else if (MODE == 2) v = extra[(size_t)row * 256 + col] + v + bias[col];
        C[(size_t)row * N + col] = v;
      }
    }
  }
  if (MODE == 1) {
    // fused colsum: reduce the 4 quads' 16-row partials, one atomic per col
#pragma unroll
    for (int j = 0; j < 4; j++) {
      cs[j] += __shfl_xor(cs[j], 16, 64);
      cs[j] += __shfl_xor(cs[j], 32, 64);
    }
    if (quad == 0) {
#pragma unroll
      for (int j = 0; j < 4; j++)
        atomicAdd(&part[batch * 256 + n0 + j * 16 + r16], cs[j]);
    }
  }
}

// ---------------------------------------------------------------------------
// Attention v4: BARRIER-FREE. Block=256 = one (b,n), thread t = qkv channel;
// each wave privately stages idx/rel in lanes 0..31 and broadcasts per-j via
// v_readlane (no block barrier, no rel/idx LDS, g0 waves finish early and
// free the SIMD). Folded logits via 32-lane DPP reduce; SGPR-base gathers;
// tanh gelu. LDS: logits only (1 KB), strictly intra-wave.
// ---------------------------------------------------------------------------
__device__ __forceinline__ float head32_reduce(float u) {
  u = dpp_addf<0x111>(u);
  u = dpp_addf<0x112>(u);
  u = dpp_addf<0x114>(u);
  u = dpp_addf<0x118>(u);
  u = dpp_addf<0x142>(u);
  return u;
}

template <int NK>
__device__ __forceinline__ float attn_group(const float* __restrict__ qkvb,
                                            int jidx, float jfx, float jfy,
                                            float jfz, float (*logits_s)[32],
                                            float qS, float w0, float w1,
                                            float w2, float bb, int t) {
  float rp[NK];
  int lane = t & 63;
  bool writer = ((lane & 31) == 31);
  int h = t >> 5;
#pragma unroll
  for (int j = 0; j < NK; j++) {
    int jj = __builtin_amdgcn_readlane(jidx, j);               // SGPR
    float rx = __int_as_float(__builtin_amdgcn_readlane(__float_as_int(jfx), j));
    float ry = __int_as_float(__builtin_amdgcn_readlane(__float_as_int(jfy), j));
    float rz = __int_as_float(__builtin_amdgcn_readlane(__float_as_int(jfz), j));
    const float* kr = qkvb + (size_t)jj * QKVW + 256;          // scalar base
    float kv = kr[t];                                          // coalesced
    float x = fmaf(rx, w0, fmaf(ry, w1, fmaf(rz, w2, bb)));
    float r = gelu_tanh(x);
    rp[j] = r;
    float u = head32_reduce(fmaf(qS, kv, r));
    if (writer) logits_s[h][j] = u;
  }
  __builtin_amdgcn_wave_barrier();
  asm volatile("s_waitcnt lgkmcnt(0)" ::: "memory");
  float mx = -3.4e38f;
#pragma unroll
  for (int j = 0; j < NK; j++) mx = fmaxf(mx, logits_s[h][j]);
  float num = 0.f, den = 0.f;
#pragma unroll
  for (int j = 0; j < NK; j++) {
    float e = __expf(logits_s[h][j] - mx);
    int jj = __builtin_amdgcn_readlane(jidx, j);
    const float* vr = qkvb + (size_t)jj * QKVW + 512;
    float v = vr[t];
    num = fmaf(e, v + rp[j], num);
    den += e;
  }
  return num * __builtin_amdgcn_rcpf(den);
}

__global__ __launch_bounds__(256) void attn_kernel(
    const float* __restrict__ qkv, const float* __restrict__ pos,
    const int* __restrict__ knn,
    const float* __restrict__ Wp0, const float* __restrict__ bp0,
    const float* __restrict__ Wp1, const float* __restrict__ bp1,
    ushort_t* __restrict__ xcat) {
  const float SCALE = 0.17677669529663687f;  // 32^-0.5
  int bn = blockIdx.x;
  int b = bn >> 11, n = bn & (NPT - 1);
  int t = threadIdx.x;
  int g = t >> 7, c = t & 127, lane = t & 63;
  __shared__ float logits_s[8][32];
  const float* qkvb = qkv + (size_t)b * NPT * QKVW;
  // per-wave staging: lanes 0..31 hold neighbor idx + rel (no LDS, no barrier)
  int jidx = 0;
  float jfx = 0.f, jfy = 0.f, jfz = 0.f;
  if (lane < 32) {
    jidx = knn[(size_t)bn * 32 + lane];
    const float* pn = pos + ((size_t)b * NPT + n) * 3;
    const float* pj = pos + ((size_t)b * NPT + jidx) * 3;
    jfx = pn[0] - pj[0];
    jfy = pn[1] - pj[1];
    jfz = pn[2] - pj[2];
  }
  float q = qkvb[(size_t)n * QKVW + t];
  const float* Wp = g ? Wp1 : Wp0;
  const float* bp = g ? bp1 : bp0;
  float w0 = Wp[c], w1 = Wp[128 + c], w2 = Wp[256 + c], bb = bp[c];
  float qS = q * SCALE;
  float o = (g == 0)
      ? attn_group<16>(qkvb, jidx, jfx, jfy, jfz, logits_s, qS, w0, w1, w2, bb, t)
      : attn_group<32>(qkvb, jidx, jfx, jfy, jfz, logits_s, qS, w0, w1, w2, bb, t);
  xcat[((size_t)b * NPT + n) * DIM_ + t] = f2bf(o);
}

// ---------------------------------------------------------------------------
// MSF MLP + gate fold: S = part/2048 -> Z=gelu(S@Wfc1+b) -> av=softmax pair
// -> avWheadT[b][n][k] = bf16(WheadT[n][k]*av[b][k]). One block per batch.
// ---------------------------------------------------------------------------
__global__ __launch_bounds__(256) void msf_small_kernel(
    const float* __restrict__ part, const float* __restrict__ Wfc1,
    const float* __restrict__ bfc1, const float* __restrict__ Wfc2,
    const float* __restrict__ bfc2, const ushort_t* __restrict__ WheadT,
    ushort_t* __restrict__ avWheadT) {
  int b = blockIdx.x, t = threadIdx.x;
  __shared__ float S[256], Z[128], A[256];
  S[t] = part[b * 256 + t] * (1.0f / 2048.0f);
  __syncthreads();
  if (t < 128) {
    float z = bfc1[t];
    for (int i = 0; i < 256; i++) z += S[i] * Wfc1[i * 128 + t];
    Z[t] = gelu_f(z);
  }
  __syncthreads();
  float a = bfc2[t];
  for (int j = 0; j < 128; j++) a += Z[j] * Wfc2[j * 256 + t];
  A[t] = a;
  __syncthreads();
  float pA = A[t ^ 128];
  float m = fmaxf(a, pA);
  float e = expf(a - m);
  float av = e / (e + expf(pA - m));
  ushort_t* ot = avWheadT + (size_t)b * 65536;
  for (int n = 0; n < 256; n++)
    ot[n * 256 + t] = f2bf(bf2f(WheadT[n * 256 + t]) * av);
}

// ---------------------------------------------------------------------------
extern "C" void kernel_launch(void* const* d_in, const int* in_sizes, int n_in,
                              void* d_out, int out_size, void* d_ws, size_t ws_size,
                              hipStream_t stream) {
  const float* x     = (const float*)d_in[0];
  const float* pos   = (const float*)d_in[1];
  const float* Wqkv  = (const float*)d_in[2];
  const float* Wp0   = (const float*)d_in[3];
  const float* bp0   = (const float*)d_in[4];
  const float* Wp1   = (const float*)d_in[5];
  const float* bp1   = (const float*)d_in[6];
  const float* Wproj = (const float*)d_in[7];
  const float* bproj = (const float*)d_in[8];
  const float* Wfc1  = (const float*)d_in[9];
  const float* bfc1  = (const float*)d_in[10];
  const float* Wfc2  = (const float*)d_in[11];
  const float* bfc2  = (const float*)d_in[12];
  const float* Whead = (const float*)d_in[13];
  const float* bhead = (const float*)d_in[14];
  float* out = (float*)d_out;

  char* ws = (char*)d_ws;
  size_t off = 0;
  int* idx = (int*)(ws + off);            off += (size_t)B_ * NPT * 32 * 4;     // 1.0 MB
  float* qkv = (float*)(ws + off);        off += (size_t)B_ * NPT * QKVW * 4;   // 25.2 MB
  float* fp = qkv;  // feats_proj reuses qkv region (qkv dead after attn)
  ushort_t* xbf = (ushort_t*)(ws + off);  off += (size_t)B_ * NPT * DIM_ * 2;   // 4.2 MB
  ushort_t* xcat = xbf;  // xbf dead after gemm0; attn writes xcat here
  ushort_t* WqkvT = (ushort_t*)(ws + off);  off += (size_t)QLEN * 2;
  ushort_t* WprojT = (ushort_t*)(ws + off); off += (size_t)PLEN * 2;
  ushort_t* WheadT = (ushort_t*)(ws + off); off += (size_t)PLEN * 2;
  ushort_t* avWheadT = (ushort_t*)(ws + off); off += (size_t)B_ * PLEN * 2;
  float* part = (float*)(ws + off);       off += 1024 * 4;                       // [B][256]

  const int M = B_ * NPT;  // 8192

  convert_kernel<<<(XLEN + QLEN + 2 * PLEN) / 256, 256, 0, stream>>>(
      x, Wqkv, Wproj, Whead, xbf, WqkvT, WprojT, WheadT, part);
  knn_kernel<<<M / 4, 256, 0, stream>>>(pos, idx);
  gemm_rf<0><<<dim3(QKVW / 64, M / 64), 64, 0, stream>>>(
      xbf, WqkvT, nullptr, nullptr, qkv, nullptr, QKVW);
  attn_kernel<<<M, 256, 0, stream>>>(qkv, pos, idx, Wp0, bp0, Wp1, bp1, xcat);
  gemm_rf<1><<<dim3(DIM_ / 64, M / 64), 64, 0, stream>>>(
      xcat, WprojT, bproj, nullptr, fp, part, DIM_);
  msf_small_kernel<<<B_, 256, 0, stream>>>(part, Wfc1, bfc1, Wfc2, bfc2,
                                           WheadT, avWheadT);
  gemm_rf<2><<<dim3(DIM_ / 64, M / 64), 64, 0, stream>>>(
      xcat, avWheadT, bhead, fp, out, nullptr, DIM_);
}